// Round 1
// 85.500 us; speedup vs baseline: 1.0219x; 1.0219x over previous
//
#include <hip/hip_runtime.h>

// CostVolume3D: B=8 H=128 W=256 C=8, D=23.
//
// Identity recap: out_flat[L], L over [B*D,H,W]; every tensor index is
// flat/23 of the source. KEY: for an ALIGNED chunk L in [23t, 23t+23):
//   - wflow index L/23 == t           -> disp, frac(-disp), k0 chunk-constant
//   - feat_l idx = 8t + (8j+c)/23     -> 184t/23 = 8t EXACT: static offsets,
//                                        two aligned float4 loads, no selects
//   - feat_r tap = 8t + floor((8j+c+8k0)/23)  (rowbase+x0 == L+k0 when no
//     clamp binds; row crossings cancel) -> one <=10-float window per chunk,
//     per-tap extraction = 1 FMA with a per-thread 23-entry carry table.
// Clamp/n-crossing can only bind when w0 = 23t mod 256 in [0,11] u [222,255]
// (k0 in [-12,11] always since wflow in [0,1), shift in [-11,11]) -> STATIC
// 210/46 split. Kernel 1: fast path for ALL chunks (garbage on the 46/256
// edge chunks), LDS-transposed coalesced float4 stores. Kernel 2: overwrite
// edge-chunk outputs with the original exact per-output code.

#define BB 8
#define HH 128
#define WW 256
#define CC 8
#define DD 23
#define NOUT   (BB * HH * WW * DD)         // 6,029,312
#define NCHUNK (NOUT / DD)                 // 262,144 = 1024 * 256
#define NGRP   (NCHUNK / 256)              // 1024
#define FEAT_MAXQ (BB * HH * WW * CC - 1)  // 2,097,151
#define N2 (46 * NGRP * DD)                // 1,083,392 edge outputs

__global__ __launch_bounds__(256) void costvol_fast(
    const float* __restrict__ feat_l,
    const float* __restrict__ feat_r,
    const float* __restrict__ wflow,
    float* __restrict__ out)
{
    __shared__ float lds[256 * DD];        // 23,552 B
    const unsigned tid = threadIdx.x;
    const unsigned t   = blockIdx.x * 256u + tid;   // chunk id < 262144

    // ---- chunk-constant scalars ----
    const unsigned L0   = t * 23u;
    const unsigned n    = L0 >> 15;        // b*23 + d (constant: no crossing in fast set)
    const unsigned nmod = n % 23u;
    const float shiftf  = (float)(int)nmod - 11.0f;
    const float disp    = wflow[t] - shiftf;
    const float nd      = -disp;
    const float k0f     = floorf(nd);
    const float frac    = nd - k0f;        // = frac(wp - disp) for integer wp
    int k0 = (int)k0f;
    k0 = min(max(k0, -12), 11);            // guaranteed range; clamp for safety
    const int u  = 8 * k0;                 // [-96, 88]
    const int qb = (u + 115) / 23 - 5;     // floor(u/23)  (115 = 5*23 keeps numerator >=0)
    const int ru = u - 23 * qb;            // [0, 22]

    // ---- feat_l: 8 aligned floats, static per-(j,c) indexing ----
    const float4 a0 = reinterpret_cast<const float4*>(feat_l)[2u * t];
    const float4 a1 = reinterpret_cast<const float4*>(feat_l)[2u * t + 1u];
    const float a[8] = {a0.x, a0.y, a0.z, a0.w, a1.x, a1.y, a1.z, a1.w};

    // ---- feat_r: <=10-float contiguous window (clamped for edge chunks) ----
    const int wb = (int)(8u * t) + qb;
    float w[10];
    #pragma unroll
    for (int i = 0; i < 10; ++i) {
        int idx = min(max(wb + i, 0), FEAT_MAXQ);
        w[i] = feat_r[idx];
    }
    float dw[9];
    #pragma unroll
    for (int i = 0; i < 9; ++i) dw[i] = w[i + 1] - w[i];

    // carry flag per residue class: tap(p) = w[p/23] + cf[p%23]*dw[p/23]
    float cf[23];
    #pragma unroll
    for (int r = 0; r < 23; ++r) cf[r] = (r + ru >= 23) ? 1.0f : 0.0f;

    const float m_one  = frac - 1.0f;      // -(1-frac)
    const float m_frac = -frac;

    // ---- main: 23 outputs, V1(j) == V0(j+1) sliding taps ----
    float U0[8], U1[8];
    #pragma unroll
    for (int c = 0; c < 8; ++c)
        U0[c] = fmaf(cf[c % 23], dw[c / 23], w[c / 23]);   // j=0, p=c

    const unsigned ldsBase = tid * 23u;
    #pragma unroll
    for (int j = 0; j < 23; ++j) {
        #pragma unroll
        for (int c = 0; c < 8; ++c) {
            const int p = 8 * (j + 1) + c;                 // static
            U1[c] = fmaf(cf[p % 23], dw[p / 23], w[p / 23]);
        }
        float acc = 0.0f;
        #pragma unroll
        for (int c = 0; c < 8; ++c) {
            const int pa = 8 * j + c;                      // static
            float d = fmaf(m_one,  U0[c], a[pa / 23]);     // a - (1-f)*V0
            d       = fmaf(m_frac, U1[c], d);              //   - f*V1
            acc += fabsf(d);
        }
        lds[ldsBase + j] = acc;
        #pragma unroll
        for (int c = 0; c < 8; ++c) U0[c] = U1[c];
    }

    __syncthreads();

    // ---- coalesced float4 store of the block's contiguous 5888 floats ----
    const float4* lds4 = reinterpret_cast<const float4*>(lds);
    float4* out4 = reinterpret_cast<float4*>(out);
    const unsigned base4 = blockIdx.x * 1472u;             // 5888/4
    #pragma unroll
    for (int it = 0; it < 6; ++it) {
        unsigned i = (unsigned)it * 256u + tid;
        if (i < 1472u) out4[base4 + i] = lds4[i];
    }
}

// Edge kernel: exact original per-output code over the 46/256 edge chunks.
__global__ __launch_bounds__(256) void costvol_edge(
    const float* __restrict__ feat_l,
    const float* __restrict__ feat_r,
    const float* __restrict__ wflow,
    float* __restrict__ out)
{
    unsigned g = blockIdx.x * 256u + threadIdx.x;
    if (g >= (unsigned)N2) return;

    // dense edge index -> (group a, edge residue r, j) -> chunk t -> L
    unsigned sc = g / 23u;
    unsigned j  = g - sc * 23u;
    unsigned aG = sc / 46u;
    unsigned r  = sc - aG * 46u;
    unsigned w0 = r + (r < 12u ? 0u : 210u);     // [0,11] u [222,255]
    unsigned s  = (167u * w0) & 255u;            // 167 = 23^-1 mod 256
    unsigned L  = ((aG << 8) + s) * 23u + j;

    // ---- original per-output body (handles clip / row & n crossings) ----
    unsigned n  = L >> 15;
    unsigned wp = L & (WW - 1);

    unsigned nmod = n % 23u;
    float shiftf = (float)(int)nmod - 11.0f;

    float disp = wflow[L / 23u] - shiftf;
    float xq   = (float)wp - disp;
    float x0f  = floorf(xq);
    float frac = xq - x0f;
    int x0i = (int)x0f;
    x0i = min(max(x0i, 0), WW - 1);
    int x1i = min(x0i + 1, WW - 1);

    unsigned rowbase = L - wp;
    unsigned baseL = L * 8u;
    unsigned base0 = (rowbase + (unsigned)x0i) * 8u;
    unsigned base1 = (rowbase + (unsigned)x1i) * 8u;

    unsigned qL = baseL / 23u; unsigned rL = baseL - qL * 23u;
    unsigned q0 = base0 / 23u; unsigned r0 = base0 - q0 * 23u;
    unsigned q1 = base1 / 23u; unsigned r1 = base1 - q1 * 23u;

    float aLo  = feat_l[qL];
    float aHi  = feat_l[min(qL + 1u, (unsigned)FEAT_MAXQ)];
    float b0Lo = feat_r[q0];
    float b0Hi = feat_r[min(q0 + 1u, (unsigned)FEAT_MAXQ)];
    float b1Lo = feat_r[q1];
    float b1Hi = feat_r[min(q1 + 1u, (unsigned)FEAT_MAXQ)];

    int sL = 23 - (int)rL;
    int s0 = 23 - (int)r0;
    int s1 = 23 - (int)r1;

    float one_m = 1.0f - frac;
    float acc = 0.0f;
    #pragma unroll
    for (int c = 0; c < 8; ++c) {
        float A  = (c < sL) ? aLo  : aHi;
        float V0 = (c < s0) ? b0Lo : b0Hi;
        float V1 = (c < s1) ? b1Lo : b1Hi;
        float wv = V0 * one_m + V1 * frac;
        acc += fabsf(A - wv);
    }
    out[L] = acc;
}

extern "C" void kernel_launch(void* const* d_in, const int* in_sizes, int n_in,
                              void* d_out, int out_size, void* d_ws, size_t ws_size,
                              hipStream_t stream) {
    const float* feat_l = (const float*)d_in[0];
    const float* feat_r = (const float*)d_in[1];
    const float* wflow  = (const float*)d_in[2];
    float* out = (float*)d_out;

    // Pass 1: all 262,144 chunks, fast path, coalesced stores (edge chunks garbage).
    costvol_fast<<<NGRP, 256, 0, stream>>>(feat_l, feat_r, wflow, out);
    // Pass 2: overwrite the 1,083,392 edge outputs with exact per-output code.
    costvol_edge<<<(N2 + 255) / 256, 256, 0, stream>>>(feat_l, feat_r, wflow, out);
}

// Round 2
// 83.579 us; speedup vs baseline: 1.0454x; 1.0230x over previous
//
#include <hip/hip_runtime.h>

// CostVolume3D: B=8 H=128 W=256 C=8, D=23 — fused single-dispatch version.
//
// Identity: out_flat[L] with per-chunk structure for L in [23t, 23t+23):
//   wflow idx L/23 == t (exactly, for ALL chunks) -> disp base hoisted.
//   feat_l idx = 8t + (8j+c)/23  (184t/23 = 8t exact, static offsets).
//   feat_r tap = 8t + qb + (p+ru)/23, p = 8j+c, u = 8*floor(-disp) = 23qb+ru
//     -> one 10-float contiguous window + carry-FMA per tap (static indices).
// Edge-ness (x-clamp / row / n crossing possible) is a pure function of
// w0 = 23t mod 256: edge iff w0 in [0,11] u [222,255]  <=>
// ((23t+34)&255) < 46. 46/256 residues. Within each block we build a
// permutation packing the 46 edge residues into lanes 0..45 (wave 0), so
// waves 1..3 are pure fast path; wave 0 runs the proven per-output slow
// path for edge chunks. LDS transpose -> coalesced float4 stores.
//
// Fast-class proofs (w0 in [12,221]): wp = w0+j in [12,243] => no row/n
// crossing; x0 = wp+k0 in [0,254] (k0 in [-12,11] since wflow in [0,1),
// shift in [-11,11]) => no clamp binds, x1 = x0+1 <= 255; window
// [8t+qb, 8t+qb+9] stays inside feat bounds => clamp-free loads.

#define BB 8
#define HH 128
#define WW 256
#define CC 8
#define DD 23
#define NOUT   (BB * HH * WW * DD)         // 6,029,312
#define NCHUNK (NOUT / DD)                 // 262,144
#define NGRP   (NCHUNK / 256)              // 1024
#define FEAT_MAXQ (BB * HH * WW * CC - 1)  // 2,097,151

__global__ __launch_bounds__(256) void costvol_fused(
    const float* __restrict__ feat_l,
    const float* __restrict__ feat_r,
    const float* __restrict__ wflow,
    float* __restrict__ out)
{
    __shared__ float lds[256 * DD];        // 23,552 B
    __shared__ unsigned char perm[256];
    __shared__ unsigned wecnt[4];

    const unsigned tid = threadIdx.x;

    // ---- within-block permutation: edge residues -> slots 0..45 ----
    const bool edgeRes = ((23u * tid + 34u) & 255u) < 46u;
    const unsigned long long bal = __ballot(edgeRes);
    const unsigned wv = tid >> 6, ln = tid & 63u;
    if (ln == 0u) wecnt[wv] = (unsigned)__popcll(bal);
    __syncthreads();
    unsigned epre = 0;
    #pragma unroll
    for (unsigned w = 0; w < 4u; ++w) epre += (w < wv) ? wecnt[w] : 0u;
    const unsigned ebw = (unsigned)__popcll(bal & ((1ull << ln) - 1ull));
    const unsigned edgesBefore = epre + ebw;
    const unsigned slot = edgeRes ? edgesBefore : 46u + (tid - edgesBefore);
    perm[slot] = (unsigned char)tid;
    __syncthreads();

    const unsigned res = perm[tid];
    const unsigned t   = blockIdx.x * 256u + res;   // this thread's chunk
    const unsigned ldsBase = res * 23u;
    const float wbase = wflow[t];                   // wflow[L/23] == wflow[t] for all j

    if (tid >= 46u) {
        // ================= FAST PATH (no clamps, no crossings) =================
        const unsigned n    = (t * 23u) >> 15;      // constant across chunk
        const unsigned nmod = n % 23u;
        const float shiftf  = (float)(int)nmod - 11.0f;
        const float nd   = shiftf - wbase;          // -disp
        const float k0f  = floorf(nd);
        const float frac = nd - k0f;                // = w1 for every j (wp integer)
        int k0 = (int)k0f;
        k0 = min(max(k0, -12), 11);                 // guaranteed range; safety only
        const int u  = 8 * k0;                      // [-96, 88]
        const int qb = (u + 115) / 23 - 5;          // floor(u/23)
        const int ru = u - 23 * qb;                 // [0, 22]

        const float4 a0 = reinterpret_cast<const float4*>(feat_l)[2u * t];
        const float4 a1 = reinterpret_cast<const float4*>(feat_l)[2u * t + 1u];
        const float a[8] = {a0.x, a0.y, a0.z, a0.w, a1.x, a1.y, a1.z, a1.w};

        const float* wr = feat_r + ((int)(8u * t) + qb);  // in-bounds for fast class
        float w[10];
        #pragma unroll
        for (int i = 0; i < 10; ++i) w[i] = wr[i];
        float dw[9];
        #pragma unroll
        for (int i = 0; i < 9; ++i) dw[i] = w[i + 1] - w[i];
        float cf[23];                               // carry per residue class
        #pragma unroll
        for (int r = 0; r < 23; ++r) cf[r] = (r + ru >= 23) ? 1.0f : 0.0f;

        const float m_one  = frac - 1.0f;           // -(1-frac)
        const float m_frac = -frac;

        float U0[8], U1[8];
        #pragma unroll
        for (int c = 0; c < 8; ++c)
            U0[c] = fmaf(cf[c], dw[0], w[0] * 0.0f + w[0]);  // p=c: cf[c]*dw[0]+w[0]
        #pragma unroll
        for (int c = 0; c < 8; ++c)
            U0[c] = fmaf(cf[c], dw[0], w[0]);

        #pragma unroll
        for (int j = 0; j < 23; ++j) {
            #pragma unroll
            for (int c = 0; c < 8; ++c) {
                const int p = 8 * (j + 1) + c;      // static
                U1[c] = fmaf(cf[p % 23], dw[p / 23], w[p / 23]);
            }
            float acc = 0.0f;
            #pragma unroll
            for (int c = 0; c < 8; ++c) {
                const int pa = 8 * j + c;           // static, pa/23 <= 7
                float d = fmaf(m_one,  U0[c], a[pa / 23]);
                d       = fmaf(m_frac, U1[c], d);
                acc += fabsf(d);
            }
            lds[ldsBase + (unsigned)j] = acc;
            #pragma unroll
            for (int c = 0; c < 8; ++c) U0[c] = U1[c];
        }
    } else {
        // ================= SLOW PATH (proven per-output code) =================
        const unsigned Lc = t * 23u;
        for (unsigned j = 0; j < 23u; ++j) {
            const unsigned L  = Lc + j;
            const unsigned n  = L >> 15;
            const unsigned wp = L & (WW - 1);
            const unsigned nmod = n % 23u;
            const float shiftf = (float)(int)nmod - 11.0f;

            const float disp = wbase - shiftf;
            const float xq   = (float)wp - disp;
            const float x0f  = floorf(xq);
            const float frac = xq - x0f;
            int x0i = (int)x0f;
            x0i = min(max(x0i, 0), WW - 1);
            const int x1i = min(x0i + 1, WW - 1);

            const unsigned rowbase = L - wp;
            const unsigned baseL = L * 8u;
            const unsigned base0 = (rowbase + (unsigned)x0i) * 8u;
            const unsigned base1 = (rowbase + (unsigned)x1i) * 8u;

            const unsigned qL = baseL / 23u; const unsigned rL = baseL - qL * 23u;
            const unsigned q0 = base0 / 23u; const unsigned r0 = base0 - q0 * 23u;
            const unsigned q1 = base1 / 23u; const unsigned r1 = base1 - q1 * 23u;

            const float aLo  = feat_l[qL];
            const float aHi  = feat_l[min(qL + 1u, (unsigned)FEAT_MAXQ)];
            const float b0Lo = feat_r[q0];
            const float b0Hi = feat_r[min(q0 + 1u, (unsigned)FEAT_MAXQ)];
            const float b1Lo = feat_r[q1];
            const float b1Hi = feat_r[min(q1 + 1u, (unsigned)FEAT_MAXQ)];

            const int sL = 23 - (int)rL;
            const int s0 = 23 - (int)r0;
            const int s1 = 23 - (int)r1;

            const float one_m = 1.0f - frac;
            float acc = 0.0f;
            #pragma unroll
            for (int c = 0; c < 8; ++c) {
                const float A  = (c < sL) ? aLo  : aHi;
                const float V0 = (c < s0) ? b0Lo : b0Hi;
                const float V1 = (c < s1) ? b1Lo : b1Hi;
                const float wv2 = V0 * one_m + V1 * frac;
                acc += fabsf(A - wv2);
            }
            lds[ldsBase + j] = acc;
        }
    }

    __syncthreads();

    // ---- coalesced float4 store of the block's contiguous 5888 floats ----
    const float4* lds4 = reinterpret_cast<const float4*>(lds);
    float4* out4 = reinterpret_cast<float4*>(out);
    const unsigned base4 = blockIdx.x * 1472u;      // 5888/4
    #pragma unroll
    for (int it = 0; it < 6; ++it) {
        const unsigned i = (unsigned)it * 256u + tid;
        if (i < 1472u) out4[base4 + i] = lds4[i];
    }
}

extern "C" void kernel_launch(void* const* d_in, const int* in_sizes, int n_in,
                              void* d_out, int out_size, void* d_ws, size_t ws_size,
                              hipStream_t stream) {
    const float* feat_l = (const float*)d_in[0];
    const float* feat_r = (const float*)d_in[1];
    const float* wflow  = (const float*)d_in[2];
    float* out = (float*)d_out;

    costvol_fused<<<NGRP, 256, 0, stream>>>(feat_l, feat_r, wflow, out);
}